// Round 10
// baseline (1413.763 us; speedup 1.0000x reference)
//
#include <hip/hip_runtime.h>
#include <hip/hip_bf16.h>
#include <math.h>

#define B_  2
#define N_  1024
#define E_  768
#define H_  12
#define HD_ 64
#define L_  6
#define FF_ 3072
#define V_  50257
#define VPAD_ 50304
#define QKVW_ 2304
#define M_  (B_ * N_)   // 2048

// per-layer transposed-weight slab (bf16 element offsets)
#define OFF_QKV_ 0
#define OFF_WO_  (QKVW_ * E_)
#define OFF_W1_  (OFF_WO_ + E_ * E_)
#define OFF_W2_  (OFF_W1_ + FF_ * E_)
#define WSLAB_   ((size_t)(OFF_W2_ + E_ * FF_))   // 7077888 elems

typedef short short8 __attribute__((ext_vector_type(8)));
typedef float f32x4 __attribute__((ext_vector_type(4)));

__device__ __forceinline__ float gelu_f(float x) {
  return 0.5f * x * (1.0f + tanhf(0.7978845608028654f * (x + 0.044715f * x * x * x)));
}

__device__ __forceinline__ unsigned short f2bf(float f) {
  __hip_bfloat16 b = __float2bfloat16(f);
  return *reinterpret_cast<unsigned short*>(&b);
}

__device__ __forceinline__ void async_ld16(const void* g, void* l) {
  __builtin_amdgcn_global_load_lds(
      (const __attribute__((address_space(1))) void*)g,
      (__attribute__((address_space(3))) void*)l, 16, 0, 0);
}

// ---------------- embed ----------------
__global__ __launch_bounds__(256) void embed_kernel(const int* __restrict__ x,
    const float* __restrict__ tok, float* __restrict__ h) {
  int idx = blockIdx.x * 256 + threadIdx.x;
  const int total = B_ * N_ * E_;
  if (idx >= total) return;
  int e  = idx % E_;
  int bn = idx / E_;
  int n  = bn % N_;
  int t  = x[bn];
  float freq = expf(-9.210340371976184f * (float)(2 * e) / (float)E_);
  float arg  = (float)n * freq;
  float pe   = (e & 1) ? cosf(arg) : sinf(arg);
  h[idx] = tok[(size_t)t * E_ + e] + pe;
}

// ---------------- layernorm: fp32 in -> bf16 out ----------------
__global__ __launch_bounds__(256) void layernorm_kernel(const float* __restrict__ in,
    __hip_bfloat16* __restrict__ out, const float* __restrict__ g, const float* __restrict__ b) {
  int row = blockIdx.x;
  const float* xr = in + (size_t)row * E_;
  __shared__ float red[256];
  int tid = threadIdx.x;
  float s = 0.f, ss = 0.f;
  for (int e = tid; e < E_; e += 256) { float v = xr[e]; s += v; ss += v * v; }
  red[tid] = s; __syncthreads();
  for (int o = 128; o > 0; o >>= 1) { if (tid < o) red[tid] += red[tid + o]; __syncthreads(); }
  float mean = red[0] / (float)E_;
  __syncthreads();
  red[tid] = ss; __syncthreads();
  for (int o = 128; o > 0; o >>= 1) { if (tid < o) red[tid] += red[tid + o]; __syncthreads(); }
  float var = red[0] / (float)E_ - mean * mean;
  float inv = rsqrtf(var + 1e-5f);
  for (int e = tid; e < E_; e += 256)
    out[(size_t)row * E_ + e] = __float2bfloat16(g[e] * (xr[e] - mean) * inv + b[e]);
}

// ---------------- transpose + cast (head weight) ----------------
__global__ __launch_bounds__(256) void transpose_cast_kernel(const float* __restrict__ in,
    __hip_bfloat16* __restrict__ out, int K, int Nn) {
  __shared__ float t[64][65];
  int k0 = blockIdx.x * 64, n0 = blockIdx.y * 64;
  int tid = threadIdx.x;
  int c = tid & 63, rg = tid >> 6;
#pragma unroll
  for (int i = 0; i < 16; ++i) {
    int r = rg * 16 + i;
    int n = n0 + c;
    t[r][c] = (n < Nn) ? in[(size_t)(k0 + r) * Nn + n] : 0.0f;
  }
  __syncthreads();
#pragma unroll
  for (int i = 0; i < 16; ++i) {
    int ro = rg * 16 + i;
    out[(size_t)(n0 + ro) * K + (k0 + c)] = __float2bfloat16(t[c][ro]);
  }
}

// ---------------- per-layer weight transposes ----------------
__global__ __launch_bounds__(256) void wtrans_kernel(
    const float* __restrict__ wq, const float* __restrict__ wk,
    const float* __restrict__ wv, const float* __restrict__ wo,
    const float* __restrict__ w1, const float* __restrict__ w2,
    __hip_bfloat16* __restrict__ out, int l0) {
  int bid = blockIdx.x;
  int lay = bid / 1728;
  int t = bid - lay * 1728;
  int lsrc = l0 + lay;
  __hip_bfloat16* ob = out + (size_t)lay * WSLAB_;
  const float* src; __hip_bfloat16* dst;
  int K, Nn, ntk;
  if (t < 576) {
    int which = t / 144; t -= which * 144;
    K = E_; Nn = E_; ntk = 12;
    if (which == 0)      { src = wq + (size_t)lsrc * E_ * E_; dst = ob + OFF_QKV_; }
    else if (which == 1) { src = wk + (size_t)lsrc * E_ * E_; dst = ob + OFF_QKV_ + (size_t)E_ * E_; }
    else if (which == 2) { src = wv + (size_t)lsrc * E_ * E_; dst = ob + OFF_QKV_ + (size_t)2 * E_ * E_; }
    else                 { src = wo + (size_t)lsrc * E_ * E_; dst = ob + OFF_WO_; }
  } else if (t < 1152) {
    t -= 576; K = E_; Nn = FF_; ntk = 12;
    src = w1 + (size_t)lsrc * E_ * FF_; dst = ob + OFF_W1_;
  } else {
    t -= 1152; K = FF_; Nn = E_; ntk = 48;
    src = w2 + (size_t)lsrc * FF_ * E_; dst = ob + OFF_W2_;
  }
  int kt = t % ntk, nt = t / ntk;
  int k0 = kt * 64, n0 = nt * 64;
  __shared__ float tt[64][65];
  int tid = threadIdx.x;
  int c = tid & 63, rg = tid >> 6;
#pragma unroll
  for (int i = 0; i < 16; ++i) {
    int r = rg * 16 + i;
    tt[r][c] = src[(size_t)(k0 + r) * Nn + n0 + c];
  }
  __syncthreads();
#pragma unroll
  for (int i = 0; i < 16; ++i) {
    int ro = rg * 16 + i;
    dst[(size_t)(n0 + ro) * K + (k0 + c)] = __float2bfloat16(tt[c][ro]);
  }
}

// ---------------- layer MFMA GEMM: C[BM x 64 per block] = A @ Bt^T ----------------
// (unchanged from r8: BK=64 rows, conflict-free row-XOR swizzle, 2-phase dbuf)
template<int BM>
__global__ __launch_bounds__(256) void gemm_bt_kernel(
    const __hip_bfloat16* __restrict__ A, const __hip_bfloat16* __restrict__ Bt,
    const float* __restrict__ bias, const float* __restrict__ R,
    float* __restrict__ Cf, __hip_bfloat16* __restrict__ Cb,
    __hip_bfloat16* __restrict__ vt,
    int Nn, int K, int flags) {
  constexpr int NROWS = BM + 64;
  constexpr int WRT = BM / 4;        // wave row-tile
  constexpr int MF  = WRT / 16;      // m-fragments per wave
  __shared__ __align__(16) unsigned short SM[2 * NROWS * 64];  // double-buffered
  int tid = threadIdx.x;
  int w = tid >> 6, l = tid & 63;
  int bx = blockIdx.x, by = blockIdx.y;
  int row0 = by * BM, col0 = bx * 64;
  int lr = l & 15, kg = l >> 4;
  const unsigned short* Ag = (const unsigned short*)A;
  const unsigned short* Bg = (const unsigned short*)Bt;
  int srow = l >> 3;                 // 0..7 within 8-row staging group
  int schunk = (l & 7) ^ srow;       // pre-swizzled source 16B-chunk (0..7)

  constexpr int NS = NROWS / 32;     // staging rounds (8 rows per wave-instr, 4 waves)
  constexpr int A8 = BM / 8;         // 8-row groups in A tile
  auto stage = [&](int buf, int k0) {
    unsigned short* As = SM + buf * (NROWS * 64);
    unsigned short* Bs = As + BM * 64;
#pragma unroll
    for (int s = 0; s < NS; ++s) {
      int idx8 = s * 4 + w;          // 8-row block index, wave-uniform
      if (idx8 < A8)
        async_ld16(Ag + (size_t)(row0 + idx8 * 8 + srow) * K + k0 + schunk * 8,
                   &As[idx8 * 8 * 64]);
      else
        async_ld16(Bg + (size_t)(col0 + (idx8 - A8) * 8 + srow) * K + k0 + schunk * 8,
                   &Bs[(idx8 - A8) * 8 * 64]);
    }
  };

  f32x4 acc[MF][4];
#pragma unroll
  for (int m = 0; m < MF; ++m)
#pragma unroll
    for (int n = 0; n < 4; ++n) acc[m][n] = (f32x4){0.f, 0.f, 0.f, 0.f};

  int nt = K >> 6;
  stage(0, 0);
  __syncthreads();                   // buf0 ready
  int cur = 0;
  for (int t = 0; t < nt; ++t) {
    if (t + 1 < nt) stage(cur ^ 1, (t + 1) << 6);   // issue next tile first
    const unsigned short* As = SM + cur * (NROWS * 64);
    const unsigned short* Bs = As + BM * 64;
#pragma unroll
    for (int hf = 0; hf < 2; ++hf) {
      short8 af[MF], bf[4];
#pragma unroll
      for (int m = 0; m < MF; ++m) {
        int r = w * WRT + m * 16 + lr;
        af[m] = *(const short8*)&As[r * 64 + ((((hf << 2) | kg)) ^ (lr & 7)) * 8];
      }
#pragma unroll
      for (int n = 0; n < 4; ++n) {
        int r = n * 16 + lr;
        bf[n] = *(const short8*)&Bs[r * 64 + ((((hf << 2) | kg)) ^ (lr & 7)) * 8];
      }
#pragma unroll
      for (int m = 0; m < MF; ++m)
#pragma unroll
        for (int n = 0; n < 4; ++n)
          acc[m][n] = __builtin_amdgcn_mfma_f32_16x16x32_bf16(af[m], bf[n], acc[m][n], 0, 0, 0);
    }
    if (t + 1 < nt) { __syncthreads(); cur ^= 1; }  // drain next tile; protect old buf
  }

  unsigned short* vtb = (unsigned short*)vt;
#pragma unroll
  for (int n = 0; n < 4; ++n) {
    int col = col0 + n * 16 + lr;
    if (col >= Nn) continue;
    float bv = bias ? bias[col] : 0.f;
    bool to_vt = (vtb != nullptr) && (col >= 2 * E_);
    int hh = 0, dd = 0;
    if (to_vt) { int c2 = col - 2 * E_; hh = c2 >> 6; dd = c2 & 63; }
#pragma unroll
    for (int m = 0; m < MF; ++m) {
#pragma unroll
      for (int j = 0; j < 4; ++j) {
        int row = row0 + w * WRT + m * 16 + kg * 4 + j;
        float val = acc[m][n][j] + bv;
        if (flags & 1) val = gelu_f(val);
        if (R) val += R[(size_t)row * Nn + col];
        if (Cf) Cf[(size_t)row * Nn + col] = val;
        if (to_vt) {
          int bz = row >> 10, nn = row & (N_ - 1);
          vtb[((size_t)(bz * H_ + hh) * HD_ + dd) * N_ + nn] = f2bf(val);
        } else if (Cb) {
          Cb[(size_t)row * Nn + col] = __float2bfloat16(val);
        }
      }
    }
  }
}

// ---------------- head GEMM: 128x128 tile, BK=32, 2-phase dbuf in 32KB LDS ----------------
// Conflict-free swizzle for 64B rows (fixed r10): within each 8-lane phase the 4
// even-lr lanes must cover 4 distinct 16B chunks -> read chunk kg^((lr>>1)&3),
// store chunk (l&3)^((l>>3)&3) (content map pos^((rowlocal>>1)&3); involution verified).
__global__ __launch_bounds__(256) void head_gemm_kernel(
    const __hip_bfloat16* __restrict__ A, const __hip_bfloat16* __restrict__ Bt,
    float* __restrict__ Cf, int Nn, int K, int nrt) {
  __shared__ __align__(16) unsigned short SM[2 * 256 * 32];   // 32 KB
  int tid = threadIdx.x;
  int w = tid >> 6, l = tid & 63;
  int wr = w >> 1, wc = w & 1;
  int bid = blockIdx.x;
  int q = gridDim.x >> 3;           // gridDim.x % 8 == 0
  int nb = (bid & 7) * q + (bid >> 3);
  int bx = nb / nrt, by = nb - bx * nrt;
  int row0 = by * 128, col0 = bx * 128;
  int lr = l & 15, kg = l >> 4;
  const unsigned short* Ag = (const unsigned short*)A;
  const unsigned short* Bg = (const unsigned short*)Bt;
  int srow = l >> 2;                       // row 0..15 within 16-row staging group
  int schunk = (l & 3) ^ ((l >> 3) & 3);   // pre-swizzled global 16B chunk (0..3)

  auto stage = [&](int buf, int k0) {
    unsigned short* As = SM + buf * (256 * 32);
    unsigned short* Bs = As + 128 * 32;
#pragma unroll
    for (int s = 0; s < 4; ++s) {
      int g = s * 4 + w;             // 16-row group 0..15, wave-uniform
      if (g < 8)
        async_ld16(Ag + (size_t)(row0 + g * 16 + srow) * K + k0 + schunk * 8,
                   &As[g * 16 * 32]);
      else
        async_ld16(Bg + (size_t)(col0 + (g - 8) * 16 + srow) * K + k0 + schunk * 8,
                   &Bs[(g - 8) * 16 * 32]);
    }
  };

  f32x4 acc[4][4];
#pragma unroll
  for (int m = 0; m < 4; ++m)
#pragma unroll
    for (int n = 0; n < 4; ++n) acc[m][n] = (f32x4){0.f, 0.f, 0.f, 0.f};

  int rchunk = (kg ^ ((lr >> 1) & 3)) * 8;
  int nt = K >> 5;                   // 24 steps at K=768
  stage(0, 0);
  __syncthreads();                   // buf0 ready
  int cur = 0;
  for (int t = 0; t < nt; ++t) {
    if (t + 1 < nt) stage(cur ^ 1, (t + 1) << 5);   // issue next tile first
    const unsigned short* As = SM + cur * (256 * 32);
    const unsigned short* Bs = As + 128 * 32;
    short8 af[4], bf[4];
#pragma unroll
    for (int m = 0; m < 4; ++m)
      af[m] = *(const short8*)&As[(wr * 64 + m * 16 + lr) * 32 + rchunk];
#pragma unroll
    for (int n = 0; n < 4; ++n)
      bf[n] = *(const short8*)&Bs[(wc * 64 + n * 16 + lr) * 32 + rchunk];
#pragma unroll
    for (int m = 0; m < 4; ++m)
#pragma unroll
      for (int n = 0; n < 4; ++n)
        acc[m][n] = __builtin_amdgcn_mfma_f32_16x16x32_bf16(af[m], bf[n], acc[m][n], 0, 0, 0);
    if (t + 1 < nt) { __syncthreads(); cur ^= 1; }  // drain next tile; protect old buf
  }

  // fp32 epilogue: LDS-transpose 32 rows/pass (2-way-free banking), coalesced nt stores
  float* Ls = (float*)SM;            // 32 x 128 fp32 = 16 KB
  bool nfull = (col0 + 128 <= Nn);
#pragma unroll
  for (int p = 0; p < 4; ++p) {
    __syncthreads();
    if (wr == (p >> 1)) {
      int mb = (p & 1) * 2;
#pragma unroll
      for (int m2 = 0; m2 < 2; ++m2)
#pragma unroll
        for (int n = 0; n < 4; ++n)
#pragma unroll
          for (int j = 0; j < 4; ++j)
            Ls[(m2 * 16 + kg * 4 + j) * 128 + ((wc * 64 + n * 16 + lr) ^ (16 * (kg & 1)))]
                = acc[mb + m2][n][j];
    }
    __syncthreads();
    int rbase = row0 + p * 32;
    if (nfull) {
#pragma unroll
      for (int i = 0; i < 16; ++i) {
        int idx = i * 256 + tid;
        int r = idx >> 7, c = idx & 127;
        float v = Ls[r * 128 + (c ^ (16 * ((r >> 2) & 1)))];
        __builtin_nontemporal_store(v, &Cf[(size_t)(rbase + r) * Nn + col0 + c]);
      }
    } else {
      for (int i = 0; i < 16; ++i) {
        int idx = i * 256 + tid;
        int r = idx >> 7, c = idx & 127;
        if (col0 + c < Nn) {
          float v = Ls[r * 128 + (c ^ (16 * ((r >> 2) & 1)))];
          __builtin_nontemporal_store(v, &Cf[(size_t)(rbase + r) * Nn + col0 + c]);
        }
      }
    }
  }
}

// ---------------- flash attention: 1 wave/block, 32 q-rows (2 groups), 32-key steps ----
// K/V fragments loaded once per K-tile and reused by both 16-row q-groups.
#define PRS_ 40
__global__ __launch_bounds__(64) void fattn_kernel(
    const __hip_bfloat16* __restrict__ qkv, const __hip_bfloat16* __restrict__ vt,
    __hip_bfloat16* __restrict__ o) {
  int qt = blockIdx.x, hh = blockIdx.y, bz = blockIdx.z;
  int q0 = qt * 32;
  int l = threadIdx.x;
  int lr = l & 15, kg = l >> 4;
  const unsigned short* base = (const unsigned short*)qkv;
  const unsigned short* vtb = (const unsigned short*)vt + ((size_t)(bz * H_ + hh)) * HD_ * N_;
  __shared__ __align__(16) unsigned short P[32 * PRS_];

  short8 qf[2][2];                        // [group][k-chunk]
#pragma unroll
  for (int g = 0; g < 2; ++g) {
    const unsigned short* qrow = base + (size_t)(bz * N_ + q0 + g * 16 + lr) * QKVW_ + hh * HD_;
#pragma unroll
    for (int c = 0; c < 2; ++c) qf[g][c] = *(const short8*)(qrow + c * 32 + kg * 8);
  }

  float mrow[2][4], lsum[2][4];
  f32x4 accO[2][4];
#pragma unroll
  for (int g = 0; g < 2; ++g)
#pragma unroll
    for (int j = 0; j < 4; ++j) { mrow[g][j] = -INFINITY; lsum[g][j] = 0.f; }
#pragma unroll
  for (int g = 0; g < 2; ++g)
#pragma unroll
    for (int db = 0; db < 4; ++db) accO[g][db] = (f32x4){0.f, 0.f, 0.f, 0.f};

  int nsteps = qt + 1;                    // keys 0 .. q0+31
  for (int kt = 0; kt < nsteps; ++kt) {
    // K fragments: shared across both q-groups
    short8 kf[2][2];
#pragma unroll
    for (int t = 0; t < 2; ++t) {
      const unsigned short* krow = base + (size_t)(bz * N_ + kt * 32 + t * 16 + lr) * QKVW_ + E_ + hh * HD_;
      kf[t][0] = *(const short8*)(krow + kg * 8);
      kf[t][1] = *(const short8*)(krow + 32 + kg * 8);
    }
    f32x4 s[2][2];
#pragma unroll
    for (int g = 0; g < 2; ++g)
#pragma unroll
      for (int t = 0; t < 2; ++t) {
        f32x4 acc = (f32x4){0.f, 0.f, 0.f, 0.f};
        acc = __builtin_amdgcn_mfma_f32_16x16x32_bf16(qf[g][0], kf[t][0], acc, 0, 0, 0);
        acc = __builtin_amdgcn_mfma_f32_16x16x32_bf16(qf[g][1], kf[t][1], acc, 0, 0, 0);
        s[g][t] = acc;
      }
#pragma unroll
    for (int g = 0; g < 2; ++g) {
      float pm[2][4];
#pragma unroll
      for (int t = 0; t < 2; ++t) {
        int kglob = kt * 32 + t * 16 + lr;
#pragma unroll
        for (int j = 0; j < 4; ++j) {
          int qglob = q0 + g * 16 + kg * 4 + j;
          pm[t][j] = (kglob <= qglob) ? s[g][t][j] * 0.125f : -INFINITY;
        }
      }
#pragma unroll
      for (int j = 0; j < 4; ++j) {
        float tm = fmaxf(pm[0][j], pm[1][j]);
        tm = fmaxf(tm, __shfl_xor(tm, 1));
        tm = fmaxf(tm, __shfl_xor(tm, 2));
        tm = fmaxf(tm, __shfl_xor(tm, 4));
        tm = fmaxf(tm, __shfl_xor(tm, 8));
        float mnew = fmaxf(mrow[g][j], tm);
        float alpha = __expf(mrow[g][j] - mnew);
        float p0 = __expf(pm[0][j] - mnew);
        float p1 = __expf(pm[1][j] - mnew);
        float rs = p0 + p1;
        rs += __shfl_xor(rs, 1);
        rs += __shfl_xor(rs, 2);
        rs += __shfl_xor(rs, 4);
        rs += __shfl_xor(rs, 8);
        lsum[g][j] = lsum[g][j] * alpha + rs;
        mrow[g][j] = mnew;
#pragma unroll
        for (int db = 0; db < 4; ++db) accO[g][db][j] *= alpha;
        P[(g * 16 + kg * 4 + j) * PRS_ + lr]      = f2bf(p0);
        P[(g * 16 + kg * 4 + j) * PRS_ + 16 + lr] = f2bf(p1);
      }
    }
    __syncthreads();
    short8 pa[2];
#pragma unroll
    for (int g = 0; g < 2; ++g)
      pa[g] = *(const short8*)&P[(g * 16 + lr) * PRS_ + kg * 8];
    // PV: V fragments shared across both q-groups
#pragma unroll
    for (int db = 0; db < 4; ++db) {
      short8 vf = *(const short8*)(vtb + (size_t)(db * 16 + lr) * N_ + kt * 32 + kg * 8);
      accO[0][db] = __builtin_amdgcn_mfma_f32_16x16x32_bf16(pa[0], vf, accO[0][db], 0, 0, 0);
      accO[1][db] = __builtin_amdgcn_mfma_f32_16x16x32_bf16(pa[1], vf, accO[1][db], 0, 0, 0);
    }
    __syncthreads();
  }
  unsigned short* ob = (unsigned short*)o;
#pragma unroll
  for (int g = 0; g < 2; ++g)
#pragma unroll
    for (int j = 0; j < 4; ++j) {
      float inv = 1.f / lsum[g][j];
      size_t orow = (size_t)(bz * N_ + q0 + g * 16 + kg * 4 + j) * E_ + hh * HD_;
#pragma unroll
      for (int db = 0; db < 4; ++db)
        ob[orow + db * 16 + lr] = f2bf(accO[g][db][j] * inv);
    }
}

extern "C" void kernel_launch(void* const* d_in, const int* in_sizes, int n_in,
                              void* d_out, int out_size, void* d_ws, size_t ws_size,
                              hipStream_t stream) {
  const int*   x     = (const int*)  d_in[0];
  const float* tok   = (const float*)d_in[1];
  const float* wq    = (const float*)d_in[2];
  const float* wk    = (const float*)d_in[3];
  const float* wv    = (const float*)d_in[4];
  const float* wo    = (const float*)d_in[5];
  const float* bo    = (const float*)d_in[6];
  const float* ln1g  = (const float*)d_in[7];
  const float* ln1b  = (const float*)d_in[8];
  const float* ln2g  = (const float*)d_in[9];
  const float* ln2b  = (const float*)d_in[10];
  const float* w1    = (const float*)d_in[11];
  const float* b1    = (const float*)d_in[12];
  const float* w2    = (const float*)d_in[13];
  const float* b2    = (const float*)d_in[14];
  const float* lnfg  = (const float*)d_in[15];
  const float* lnfb  = (const float*)d_in[16];
  const float* whead = (const float*)d_in[17];
  float* out = (float*)d_out;

  char* wsb = (char*)d_ws;
  size_t off = 0;
  auto alloc = [&](size_t bytes) -> void* {
    void* p = wsb + off; off += (bytes + 255) & ~(size_t)255; return p;
  };
  float*           h        = (float*)          alloc((size_t)M_ * E_ * 4);
  __hip_bfloat16*  y_bf     = (__hip_bfloat16*) alloc((size_t)M_ * E_ * 2);
  __hip_bfloat16*  qkv_bf   = (__hip_bfloat16*) alloc((size_t)M_ * QKVW_ * 2);
  __hip_bfloat16*  vt_bf    = (__hip_bfloat16*) alloc((size_t)B_ * H_ * HD_ * N_ * 2);
  __hip_bfloat16*  o_bf     = (__hip_bfloat16*) alloc((size_t)M_ * E_ * 2);
  __hip_bfloat16*  mid_bf   = (__hip_bfloat16*) alloc((size_t)M_ * FF_ * 2);
  __hip_bfloat16*  whead_bt = (__hip_bfloat16*) alloc((size_t)VPAD_ * E_ * 2);
  bool preall = (off + (size_t)6 * WSLAB_ * 2 <= ws_size);
  __hip_bfloat16* wslab = (__hip_bfloat16*) alloc(((size_t)(preall ? 6 : 1)) * WSLAB_ * 2);

  dim3 blk(256);

  embed_kernel<<<(B_ * N_ * E_ + 255) / 256, blk, 0, stream>>>(x, tok, h);
  transpose_cast_kernel<<<dim3(E_ / 64, VPAD_ / 64), blk, 0, stream>>>(whead, whead_bt, E_, V_);
  if (preall)
    wtrans_kernel<<<6 * 1728, blk, 0, stream>>>(wq, wk, wv, wo, w1, w2, wslab, 0);

  dim3 gqkv(QKVW_ / 64, M_ / 128);    // 36x16 = 576 blocks
  dim3 gffn1(FF_ / 64, M_ / 128);     // 48x16 = 768 blocks
  dim3 gsm(E_ / 64, M_ / 64);         // BM=64: 12x32 = 384 blocks (wo, ffn2)
  dim3 gfa(N_ / 32, H_, B_);          // 32 q-rows per block

  for (int l = 0; l < L_; ++l) {
    if (!preall)
      wtrans_kernel<<<1728, blk, 0, stream>>>(wq, wk, wv, wo, w1, w2, wslab, l);
    __hip_bfloat16* wb = wslab + (preall ? (size_t)l * WSLAB_ : 0);

    layernorm_kernel<<<M_, blk, 0, stream>>>(h, y_bf, ln1g + (size_t)l * E_, ln1b + (size_t)l * E_);
    gemm_bt_kernel<128><<<gqkv, blk, 0, stream>>>(y_bf, wb + OFF_QKV_, nullptr, nullptr,
        nullptr, qkv_bf, vt_bf, QKVW_, E_, 0);
    fattn_kernel<<<gfa, dim3(64), 0, stream>>>(qkv_bf, vt_bf, o_bf);
    gemm_bt_kernel<64><<<gsm, blk, 0, stream>>>(o_bf, wb + OFF_WO_, bo + (size_t)l * E_, h,
        h, nullptr, nullptr, E_, E_, 0);
    layernorm_kernel<<<M_, blk, 0, stream>>>(h, y_bf, ln2g + (size_t)l * E_, ln2b + (size_t)l * E_);
    gemm_bt_kernel<128><<<gffn1, blk, 0, stream>>>(y_bf, wb + OFF_W1_, b1 + (size_t)l * FF_,
        nullptr, nullptr, mid_bf, nullptr, FF_, E_, 1);
    gemm_bt_kernel<64><<<gsm, blk, 0, stream>>>(mid_bf, wb + OFF_W2_, b2 + (size_t)l * E_, h,
        h, nullptr, nullptr, E_, FF_, 0);
  }

  layernorm_kernel<<<M_, blk, 0, stream>>>(h, y_bf, lnfg, lnfb);
  // head: 128x128 tiles, BK=32 dbuf in 32KB, XCD-panel remap, fp32 nt epilogue
  head_gemm_kernel<<<dim3((VPAD_ / 128) * (M_ / 128)), blk, 0, stream>>>(
      y_bf, whead_bt, out, V_, E_, M_ / 128);
}

// Round 12
// 1307.557 us; speedup vs baseline: 1.0812x; 1.0812x over previous
//
#include <hip/hip_runtime.h>
#include <hip/hip_bf16.h>
#include <math.h>

#define B_  2
#define N_  1024
#define E_  768
#define H_  12
#define HD_ 64
#define L_  6
#define FF_ 3072
#define V_  50257
#define VPAD_ 50304
#define QKVW_ 2304
#define M_  (B_ * N_)   // 2048

// per-layer transposed-weight slab (bf16 element offsets)
#define OFF_QKV_ 0
#define OFF_WO_  (QKVW_ * E_)
#define OFF_W1_  (OFF_WO_ + E_ * E_)
#define OFF_W2_  (OFF_W1_ + FF_ * E_)
#define WSLAB_   ((size_t)(OFF_W2_ + E_ * FF_))   // 7077888 elems

typedef short short8 __attribute__((ext_vector_type(8)));
typedef float f32x4 __attribute__((ext_vector_type(4)));
typedef unsigned short u16x4 __attribute__((ext_vector_type(4)));

__device__ __forceinline__ float gelu_f(float x) {
  return 0.5f * x * (1.0f + tanhf(0.7978845608028654f * (x + 0.044715f * x * x * x)));
}

__device__ __forceinline__ unsigned short f2bf(float f) {
  __hip_bfloat16 b = __float2bfloat16(f);
  return *reinterpret_cast<unsigned short*>(&b);
}

__device__ __forceinline__ void async_ld16(const void* g, void* l) {
  __builtin_amdgcn_global_load_lds(
      (const __attribute__((address_space(1))) void*)g,
      (__attribute__((address_space(3))) void*)l, 16, 0, 0);
}

// ---------------- embed ----------------
__global__ __launch_bounds__(256) void embed_kernel(const int* __restrict__ x,
    const float* __restrict__ tok, float* __restrict__ h) {
  int idx = blockIdx.x * 256 + threadIdx.x;
  const int total = B_ * N_ * E_;
  if (idx >= total) return;
  int e  = idx % E_;
  int bn = idx / E_;
  int n  = bn % N_;
  int t  = x[bn];
  float freq = expf(-9.210340371976184f * (float)(2 * e) / (float)E_);
  float arg  = (float)n * freq;
  float pe   = (e & 1) ? cosf(arg) : sinf(arg);
  h[idx] = tok[(size_t)t * E_ + e] + pe;
}

// ---------------- layernorm: fp32 in -> bf16 out; 1 wave per row, shfl-only ----------------
__global__ __launch_bounds__(256) void layernorm_kernel(const float* __restrict__ in,
    __hip_bfloat16* __restrict__ out, const float* __restrict__ g, const float* __restrict__ b) {
  int w = threadIdx.x >> 6, lane = threadIdx.x & 63;
  int row = blockIdx.x * 4 + w;
  const float* xr = in + (size_t)row * E_;
  f32x4 v[3];
  float s = 0.f, ss = 0.f;
#pragma unroll
  for (int i = 0; i < 3; ++i) {
    v[i] = *(const f32x4*)(xr + i * 256 + lane * 4);
#pragma unroll
    for (int j = 0; j < 4; ++j) { s += v[i][j]; ss += v[i][j] * v[i][j]; }
  }
#pragma unroll
  for (int off = 1; off < 64; off <<= 1) {
    s  += __shfl_xor(s, off);
    ss += __shfl_xor(ss, off);
  }
  float mean = s * (1.0f / E_);
  float var  = ss * (1.0f / E_) - mean * mean;
  float inv  = rsqrtf(var + 1e-5f);
  unsigned short* orow = (unsigned short*)out + (size_t)row * E_;
#pragma unroll
  for (int i = 0; i < 3; ++i) {
    int e0 = i * 256 + lane * 4;
    f32x4 gv = *(const f32x4*)(g + e0);
    f32x4 bv = *(const f32x4*)(b + e0);
    u16x4 o;
#pragma unroll
    for (int j = 0; j < 4; ++j)
      o[j] = f2bf(gv[j] * (v[i][j] - mean) * inv + bv[j]);
    *(u16x4*)(orow + e0) = o;
  }
}

// ---------------- transpose + cast (head weight) ----------------
__global__ __launch_bounds__(256) void transpose_cast_kernel(const float* __restrict__ in,
    __hip_bfloat16* __restrict__ out, int K, int Nn) {
  __shared__ float t[64][65];
  int k0 = blockIdx.x * 64, n0 = blockIdx.y * 64;
  int tid = threadIdx.x;
  int c = tid & 63, rg = tid >> 6;
#pragma unroll
  for (int i = 0; i < 16; ++i) {
    int r = rg * 16 + i;
    int n = n0 + c;
    t[r][c] = (n < Nn) ? in[(size_t)(k0 + r) * Nn + n] : 0.0f;
  }
  __syncthreads();
#pragma unroll
  for (int i = 0; i < 16; ++i) {
    int ro = rg * 16 + i;
    out[(size_t)(n0 + ro) * K + (k0 + c)] = __float2bfloat16(t[c][ro]);
  }
}

// ---------------- per-layer weight transposes ----------------
__global__ __launch_bounds__(256) void wtrans_kernel(
    const float* __restrict__ wq, const float* __restrict__ wk,
    const float* __restrict__ wv, const float* __restrict__ wo,
    const float* __restrict__ w1, const float* __restrict__ w2,
    __hip_bfloat16* __restrict__ out, int l0) {
  int bid = blockIdx.x;
  int lay = bid / 1728;
  int t = bid - lay * 1728;
  int lsrc = l0 + lay;
  __hip_bfloat16* ob = out + (size_t)lay * WSLAB_;
  const float* src; __hip_bfloat16* dst;
  int K, Nn, ntk;
  if (t < 576) {
    int which = t / 144; t -= which * 144;
    K = E_; Nn = E_; ntk = 12;
    if (which == 0)      { src = wq + (size_t)lsrc * E_ * E_; dst = ob + OFF_QKV_; }
    else if (which == 1) { src = wk + (size_t)lsrc * E_ * E_; dst = ob + OFF_QKV_ + (size_t)E_ * E_; }
    else if (which == 2) { src = wv + (size_t)lsrc * E_ * E_; dst = ob + OFF_QKV_ + (size_t)2 * E_ * E_; }
    else                 { src = wo + (size_t)lsrc * E_ * E_; dst = ob + OFF_WO_; }
  } else if (t < 1152) {
    t -= 576; K = E_; Nn = FF_; ntk = 12;
    src = w1 + (size_t)lsrc * E_ * FF_; dst = ob + OFF_W1_;
  } else {
    t -= 1152; K = FF_; Nn = E_; ntk = 48;
    src = w2 + (size_t)lsrc * FF_ * E_; dst = ob + OFF_W2_;
  }
  int kt = t % ntk, nt = t / ntk;
  int k0 = kt * 64, n0 = nt * 64;
  __shared__ float tt[64][65];
  int tid = threadIdx.x;
  int c = tid & 63, rg = tid >> 6;
#pragma unroll
  for (int i = 0; i < 16; ++i) {
    int r = rg * 16 + i;
    tt[r][c] = src[(size_t)(k0 + r) * Nn + n0 + c];
  }
  __syncthreads();
#pragma unroll
  for (int i = 0; i < 16; ++i) {
    int ro = rg * 16 + i;
    dst[(size_t)(n0 + ro) * K + (k0 + c)] = __float2bfloat16(tt[c][ro]);
  }
}

// ---------------- layer MFMA GEMM: C[BM x 64 per block] = A @ Bt^T ----------------
// (r8 structure: BK=64 rows, conflict-free row-XOR swizzle, 2-phase dbuf)
template<int BM>
__global__ __launch_bounds__(256) void gemm_bt_kernel(
    const __hip_bfloat16* __restrict__ A, const __hip_bfloat16* __restrict__ Bt,
    const float* __restrict__ bias, const float* __restrict__ R,
    float* __restrict__ Cf, __hip_bfloat16* __restrict__ Cb,
    __hip_bfloat16* __restrict__ vt,
    int Nn, int K, int flags) {
  constexpr int NROWS = BM + 64;
  constexpr int WRT = BM / 4;        // wave row-tile
  constexpr int MF  = WRT / 16;      // m-fragments per wave
  __shared__ __align__(16) unsigned short SM[2 * NROWS * 64];  // double-buffered
  int tid = threadIdx.x;
  int w = tid >> 6, l = tid & 63;
  int bx = blockIdx.x, by = blockIdx.y;
  int row0 = by * BM, col0 = bx * 64;
  int lr = l & 15, kg = l >> 4;
  const unsigned short* Ag = (const unsigned short*)A;
  const unsigned short* Bg = (const unsigned short*)Bt;
  int srow = l >> 3;                 // 0..7 within 8-row staging group
  int schunk = (l & 7) ^ srow;       // pre-swizzled source 16B-chunk (0..7)

  constexpr int NS = NROWS / 32;     // staging rounds (8 rows per wave-instr, 4 waves)
  constexpr int A8 = BM / 8;         // 8-row groups in A tile
  auto stage = [&](int buf, int k0) {
    unsigned short* As = SM + buf * (NROWS * 64);
    unsigned short* Bs = As + BM * 64;
#pragma unroll
    for (int s = 0; s < NS; ++s) {
      int idx8 = s * 4 + w;          // 8-row block index, wave-uniform
      if (idx8 < A8)
        async_ld16(Ag + (size_t)(row0 + idx8 * 8 + srow) * K + k0 + schunk * 8,
                   &As[idx8 * 8 * 64]);
      else
        async_ld16(Bg + (size_t)(col0 + (idx8 - A8) * 8 + srow) * K + k0 + schunk * 8,
                   &Bs[(idx8 - A8) * 8 * 64]);
    }
  };

  f32x4 acc[MF][4];
#pragma unroll
  for (int m = 0; m < MF; ++m)
#pragma unroll
    for (int n = 0; n < 4; ++n) acc[m][n] = (f32x4){0.f, 0.f, 0.f, 0.f};

  int nt = K >> 6;
  stage(0, 0);
  __syncthreads();                   // buf0 ready
  int cur = 0;
  for (int t = 0; t < nt; ++t) {
    if (t + 1 < nt) stage(cur ^ 1, (t + 1) << 6);   // issue next tile first
    const unsigned short* As = SM + cur * (NROWS * 64);
    const unsigned short* Bs = As + BM * 64;
#pragma unroll
    for (int hf = 0; hf < 2; ++hf) {
      short8 af[MF], bf[4];
#pragma unroll
      for (int m = 0; m < MF; ++m) {
        int r = w * WRT + m * 16 + lr;
        af[m] = *(const short8*)&As[r * 64 + ((((hf << 2) | kg)) ^ (lr & 7)) * 8];
      }
#pragma unroll
      for (int n = 0; n < 4; ++n) {
        int r = n * 16 + lr;
        bf[n] = *(const short8*)&Bs[r * 64 + ((((hf << 2) | kg)) ^ (lr & 7)) * 8];
      }
#pragma unroll
      for (int m = 0; m < MF; ++m)
#pragma unroll
        for (int n = 0; n < 4; ++n)
          acc[m][n] = __builtin_amdgcn_mfma_f32_16x16x32_bf16(af[m], bf[n], acc[m][n], 0, 0, 0);
    }
    if (t + 1 < nt) { __syncthreads(); cur ^= 1; }  // drain next tile; protect old buf
  }

  unsigned short* vtb = (unsigned short*)vt;
#pragma unroll
  for (int n = 0; n < 4; ++n) {
    int col = col0 + n * 16 + lr;
    if (col >= Nn) continue;
    float bv = bias ? bias[col] : 0.f;
    bool to_vt = (vtb != nullptr) && (col >= 2 * E_);
    int hh = 0, dd = 0;
    if (to_vt) { int c2 = col - 2 * E_; hh = c2 >> 6; dd = c2 & 63; }
#pragma unroll
    for (int m = 0; m < MF; ++m) {
#pragma unroll
      for (int j = 0; j < 4; ++j) {
        int row = row0 + w * WRT + m * 16 + kg * 4 + j;
        float val = acc[m][n][j] + bv;
        if (flags & 1) val = gelu_f(val);
        if (R) val += R[(size_t)row * Nn + col];
        if (Cf) Cf[(size_t)row * Nn + col] = val;
        if (to_vt) {
          int bz = row >> 10, nn = row & (N_ - 1);
          vtb[((size_t)(bz * H_ + hh) * HD_ + dd) * N_ + nn] = f2bf(val);
        } else if (Cb) {
          Cb[(size_t)row * Nn + col] = __float2bfloat16(val);
        }
      }
    }
  }
}

// ---------------- head GEMM: 128x128 tile, BK=32, 2-phase dbuf in 32KB LDS ----------------
// Conflict-free swizzle for 64B rows (r10-verified: SQ_LDS_BANK_CONFLICT=0):
// read chunk kg^((lr>>1)&3), store chunk (l&3)^((l>>3)&3).
__global__ __launch_bounds__(256) void head_gemm_kernel(
    const __hip_bfloat16* __restrict__ A, const __hip_bfloat16* __restrict__ Bt,
    float* __restrict__ Cf, int Nn, int K, int nrt) {
  __shared__ __align__(16) unsigned short SM[2 * 256 * 32];   // 32 KB
  int tid = threadIdx.x;
  int w = tid >> 6, l = tid & 63;
  int wr = w >> 1, wc = w & 1;
  int bid = blockIdx.x;
  int q = gridDim.x >> 3;           // gridDim.x % 8 == 0
  int nb = (bid & 7) * q + (bid >> 3);
  int bx = nb / nrt, by = nb - bx * nrt;
  int row0 = by * 128, col0 = bx * 128;
  int lr = l & 15, kg = l >> 4;
  const unsigned short* Ag = (const unsigned short*)A;
  const unsigned short* Bg = (const unsigned short*)Bt;
  int srow = l >> 2;                       // row 0..15 within 16-row staging group
  int schunk = (l & 3) ^ ((l >> 3) & 3);   // pre-swizzled global 16B chunk (0..3)

  auto stage = [&](int buf, int k0) {
    unsigned short* As = SM + buf * (256 * 32);
    unsigned short* Bs = As + 128 * 32;
#pragma unroll
    for (int s = 0; s < 4; ++s) {
      int g = s * 4 + w;             // 16-row group 0..15, wave-uniform
      if (g < 8)
        async_ld16(Ag + (size_t)(row0 + g * 16 + srow) * K + k0 + schunk * 8,
                   &As[g * 16 * 32]);
      else
        async_ld16(Bg + (size_t)(col0 + (g - 8) * 16 + srow) * K + k0 + schunk * 8,
                   &Bs[(g - 8) * 16 * 32]);
    }
  };

  f32x4 acc[4][4];
#pragma unroll
  for (int m = 0; m < 4; ++m)
#pragma unroll
    for (int n = 0; n < 4; ++n) acc[m][n] = (f32x4){0.f, 0.f, 0.f, 0.f};

  int rchunk = (kg ^ ((lr >> 1) & 3)) * 8;
  int nt = K >> 5;                   // 24 steps at K=768
  stage(0, 0);
  __syncthreads();                   // buf0 ready
  int cur = 0;
  for (int t = 0; t < nt; ++t) {
    if (t + 1 < nt) stage(cur ^ 1, (t + 1) << 5);   // issue next tile first
    const unsigned short* As = SM + cur * (256 * 32);
    const unsigned short* Bs = As + 128 * 32;
    short8 af[4], bf[4];
#pragma unroll
    for (int m = 0; m < 4; ++m)
      af[m] = *(const short8*)&As[(wr * 64 + m * 16 + lr) * 32 + rchunk];
#pragma unroll
    for (int n = 0; n < 4; ++n)
      bf[n] = *(const short8*)&Bs[(wc * 64 + n * 16 + lr) * 32 + rchunk];
#pragma unroll
    for (int m = 0; m < 4; ++m)
#pragma unroll
      for (int n = 0; n < 4; ++n)
        acc[m][n] = __builtin_amdgcn_mfma_f32_16x16x32_bf16(af[m], bf[n], acc[m][n], 0, 0, 0);
    if (t + 1 < nt) { __syncthreads(); cur ^= 1; }  // drain next tile; protect old buf
  }

  // fp32 epilogue: LDS-transpose 32 rows/pass (2-way-free banking), coalesced nt stores
  float* Ls = (float*)SM;            // 32 x 128 fp32 = 16 KB
  bool nfull = (col0 + 128 <= Nn);
#pragma unroll
  for (int p = 0; p < 4; ++p) {
    __syncthreads();
    if (wr == (p >> 1)) {
      int mb = (p & 1) * 2;
#pragma unroll
      for (int m2 = 0; m2 < 2; ++m2)
#pragma unroll
        for (int n = 0; n < 4; ++n)
#pragma unroll
          for (int j = 0; j < 4; ++j)
            Ls[(m2 * 16 + kg * 4 + j) * 128 + ((wc * 64 + n * 16 + lr) ^ (16 * (kg & 1)))]
                = acc[mb + m2][n][j];
    }
    __syncthreads();
    int rbase = row0 + p * 32;
    if (nfull) {
#pragma unroll
      for (int i = 0; i < 16; ++i) {
        int idx = i * 256 + tid;
        int r = idx >> 7, c = idx & 127;
        float v = Ls[r * 128 + (c ^ (16 * ((r >> 2) & 1)))];
        __builtin_nontemporal_store(v, &Cf[(size_t)(rbase + r) * Nn + col0 + c]);
      }
    } else {
      for (int i = 0; i < 16; ++i) {
        int idx = i * 256 + tid;
        int r = idx >> 7, c = idx & 127;
        if (col0 + c < Nn) {
          float v = Ls[r * 128 + (c ^ (16 * ((r >> 2) & 1)))];
          __builtin_nontemporal_store(v, &Cf[(size_t)(rbase + r) * Nn + col0 + c]);
        }
      }
    }
  }
}

// ---------------- flash attention: 1 wave/block, 16 q-rows, 32-key steps (r9 version) ----
#define PRS_ 40
__global__ __launch_bounds__(64) void fattn_kernel(
    const __hip_bfloat16* __restrict__ qkv, const __hip_bfloat16* __restrict__ vt,
    __hip_bfloat16* __restrict__ o) {
  int qt = blockIdx.x, hh = blockIdx.y, bz = blockIdx.z;
  int q0 = qt * 16;
  int l = threadIdx.x;
  int lr = l & 15, kg = l >> 4;
  const unsigned short* base = (const unsigned short*)qkv;
  const unsigned short* vtb = (const unsigned short*)vt + ((size_t)(bz * H_ + hh)) * HD_ * N_;
  __shared__ __align__(16) unsigned short P[16 * PRS_];

  short8 qf[2];
  const unsigned short* qrow = base + (size_t)(bz * N_ + q0 + lr) * QKVW_ + hh * HD_;
#pragma unroll
  for (int c = 0; c < 2; ++c) qf[c] = *(const short8*)(qrow + c * 32 + kg * 8);

  float mrow[4], lsum[4];
  f32x4 accO[4];
#pragma unroll
  for (int j = 0; j < 4; ++j) { mrow[j] = -INFINITY; lsum[j] = 0.f; }
#pragma unroll
  for (int db = 0; db < 4; ++db) accO[db] = (f32x4){0.f, 0.f, 0.f, 0.f};

  int nsteps = (q0 + 16 + 31) / 32;
  for (int kt = 0; kt < nsteps; ++kt) {
    f32x4 s[2];
#pragma unroll
    for (int t = 0; t < 2; ++t) {
      const unsigned short* krow = base + (size_t)(bz * N_ + kt * 32 + t * 16 + lr) * QKVW_ + E_ + hh * HD_;
      short8 kf0 = *(const short8*)(krow + kg * 8);
      short8 kf1 = *(const short8*)(krow + 32 + kg * 8);
      f32x4 acc = (f32x4){0.f, 0.f, 0.f, 0.f};
      acc = __builtin_amdgcn_mfma_f32_16x16x32_bf16(qf[0], kf0, acc, 0, 0, 0);
      acc = __builtin_amdgcn_mfma_f32_16x16x32_bf16(qf[1], kf1, acc, 0, 0, 0);
      s[t] = acc;
    }
    float pm[2][4];
#pragma unroll
    for (int t = 0; t < 2; ++t) {
      int kglob = kt * 32 + t * 16 + lr;
#pragma unroll
      for (int j = 0; j < 4; ++j) {
        int qglob = q0 + kg * 4 + j;
        pm[t][j] = (kglob <= qglob) ? s[t][j] * 0.125f : -INFINITY;
      }
    }
#pragma unroll
    for (int j = 0; j < 4; ++j) {
      float tm = fmaxf(pm[0][j], pm[1][j]);
      tm = fmaxf(tm, __shfl_xor(tm, 1));
      tm = fmaxf(tm, __shfl_xor(tm, 2));
      tm = fmaxf(tm, __shfl_xor(tm, 4));
      tm = fmaxf(tm, __shfl_xor(tm, 8));
      float mnew = fmaxf(mrow[j], tm);
      float alpha = __expf(mrow[j] - mnew);
      float p0 = __expf(pm[0][j] - mnew);
      float p1 = __expf(pm[1][j] - mnew);
      float rs = p0 + p1;
      rs += __shfl_xor(rs, 1);
      rs += __shfl_xor(rs, 2);
      rs += __shfl_xor(rs, 4);
      rs += __shfl_xor(rs, 8);
      lsum[j] = lsum[j] * alpha + rs;
      mrow[j] = mnew;
#pragma unroll
      for (int db = 0; db < 4; ++db) accO[db][j] *= alpha;
      P[(kg * 4 + j) * PRS_ + lr]      = f2bf(p0);
      P[(kg * 4 + j) * PRS_ + 16 + lr] = f2bf(p1);
    }
    __syncthreads();
    short8 pa = *(const short8*)&P[lr * PRS_ + kg * 8];
#pragma unroll
    for (int db = 0; db < 4; ++db) {
      short8 vf = *(const short8*)(vtb + (size_t)(db * 16 + lr) * N_ + kt * 32 + kg * 8);
      accO[db] = __builtin_amdgcn_mfma_f32_16x16x32_bf16(pa, vf, accO[db], 0, 0, 0);
    }
    __syncthreads();
  }
  unsigned short* ob = (unsigned short*)o;
#pragma unroll
  for (int j = 0; j < 4; ++j) {
    float inv = 1.f / lsum[j];
    size_t orow = (size_t)(bz * N_ + q0 + kg * 4 + j) * E_ + hh * HD_;
#pragma unroll
    for (int db = 0; db < 4; ++db)
      ob[orow + db * 16 + lr] = f2bf(accO[db][j] * inv);
  }
}

extern "C" void kernel_launch(void* const* d_in, const int* in_sizes, int n_in,
                              void* d_out, int out_size, void* d_ws, size_t ws_size,
                              hipStream_t stream) {
  const int*   x     = (const int*)  d_in[0];
  const float* tok   = (const float*)d_in[1];
  const float* wq    = (const float*)d_in[2];
  const float* wk    = (const float*)d_in[3];
  const float* wv    = (const float*)d_in[4];
  const float* wo    = (const float*)d_in[5];
  const float* bo    = (const float*)d_in[6];
  const float* ln1g  = (const float*)d_in[7];
  const float* ln1b  = (const float*)d_in[8];
  const float* ln2g  = (const float*)d_in[9];
  const float* ln2b  = (const float*)d_in[10];
  const float* w1    = (const float*)d_in[11];
  const float* b1    = (const float*)d_in[12];
  const float* w2    = (const float*)d_in[13];
  const float* b2    = (const float*)d_in[14];
  const float* lnfg  = (const float*)d_in[15];
  const float* lnfb  = (const float*)d_in[16];
  const float* whead = (const float*)d_in[17];
  float* out = (float*)d_out;

  char* wsb = (char*)d_ws;
  size_t off = 0;
  auto alloc = [&](size_t bytes) -> void* {
    void* p = wsb + off; off += (bytes + 255) & ~(size_t)255; return p;
  };
  float*           h        = (float*)          alloc((size_t)M_ * E_ * 4);
  __hip_bfloat16*  y_bf     = (__hip_bfloat16*) alloc((size_t)M_ * E_ * 2);
  __hip_bfloat16*  qkv_bf   = (__hip_bfloat16*) alloc((size_t)M_ * QKVW_ * 2);
  __hip_bfloat16*  vt_bf    = (__hip_bfloat16*) alloc((size_t)B_ * H_ * HD_ * N_ * 2);
  __hip_bfloat16*  o_bf     = (__hip_bfloat16*) alloc((size_t)M_ * E_ * 2);
  __hip_bfloat16*  mid_bf   = (__hip_bfloat16*) alloc((size_t)M_ * FF_ * 2);
  __hip_bfloat16*  whead_bt = (__hip_bfloat16*) alloc((size_t)VPAD_ * E_ * 2);
  bool preall = (off + (size_t)6 * WSLAB_ * 2 <= ws_size);
  __hip_bfloat16* wslab = (__hip_bfloat16*) alloc(((size_t)(preall ? 6 : 1)) * WSLAB_ * 2);

  dim3 blk(256);

  embed_kernel<<<(B_ * N_ * E_ + 255) / 256, blk, 0, stream>>>(x, tok, h);
  transpose_cast_kernel<<<dim3(E_ / 64, VPAD_ / 64), blk, 0, stream>>>(whead, whead_bt, E_, V_);
  if (preall)
    wtrans_kernel<<<6 * 1728, blk, 0, stream>>>(wq, wk, wv, wo, w1, w2, wslab, 0);

  dim3 gqkv(QKVW_ / 64, M_ / 128);    // 36x16 = 576 blocks
  dim3 gffn1(FF_ / 64, M_ / 128);     // 48x16 = 768 blocks
  dim3 gsm(E_ / 64, M_ / 64);         // BM=64: 12x32 = 384 blocks (wo, ffn2)
  dim3 gfa(N_ / 16, H_, B_);          // 16 q-rows per block (r9 config)
  dim3 gln(M_ / 4);                   // 4 rows per block, 1 wave/row

  for (int l = 0; l < L_; ++l) {
    if (!preall)
      wtrans_kernel<<<1728, blk, 0, stream>>>(wq, wk, wv, wo, w1, w2, wslab, l);
    __hip_bfloat16* wb = wslab + (preall ? (size_t)l * WSLAB_ : 0);

    layernorm_kernel<<<gln, blk, 0, stream>>>(h, y_bf, ln1g + (size_t)l * E_, ln1b + (size_t)l * E_);
    gemm_bt_kernel<128><<<gqkv, blk, 0, stream>>>(y_bf, wb + OFF_QKV_, nullptr, nullptr,
        nullptr, qkv_bf, vt_bf, QKVW_, E_, 0);
    fattn_kernel<<<gfa, dim3(64), 0, stream>>>(qkv_bf, vt_bf, o_bf);
    gemm_bt_kernel<64><<<gsm, blk, 0, stream>>>(o_bf, wb + OFF_WO_, bo + (size_t)l * E_, h,
        h, nullptr, nullptr, E_, E_, 0);
    layernorm_kernel<<<gln, blk, 0, stream>>>(h, y_bf, ln2g + (size_t)l * E_, ln2b + (size_t)l * E_);
    gemm_bt_kernel<128><<<gffn1, blk, 0, stream>>>(y_bf, wb + OFF_W1_, b1 + (size_t)l * FF_,
        nullptr, nullptr, mid_bf, nullptr, FF_, E_, 1);
    gemm_bt_kernel<64><<<gsm, blk, 0, stream>>>(mid_bf, wb + OFF_W2_, b2 + (size_t)l * E_, h,
        h, nullptr, nullptr, E_, FF_, 0);
  }

  layernorm_kernel<<<gln, blk, 0, stream>>>(h, y_bf, lnfg, lnfb);
  // head: 128x128 tiles, BK=32 dbuf in 32KB, XCD-panel remap, fp32 nt epilogue
  head_gemm_kernel<<<dim3((VPAD_ / 128) * (M_ / 128)), blk, 0, stream>>>(
      y_bf, whead_bt, out, V_, E_, M_ / 128);
}